// Round 6
// baseline (422.630 us; speedup 1.0000x reference)
//
#include <hip/hip_runtime.h>
#include <hip/hip_bf16.h>

// GCN: h = relu(GCN(x,W1,b1)); h = relu(GCN(h,W2,b2)); out = h@Wfc + bfc
// GCN(x,W,b)[d] = dis[d] * ( sum_{(s,d) in E} hs[s] + hs[d] ) + b
//   where hs[v] = (x[v]@W) * dis[v],  dis[v] = rsqrt(1 + indeg(v))
//
// CSR build = two-level binned counting sort, all atomics in LDS.
// Aggregations: multi-edge dwordx4 gathers (4 edges/inst for 64-f rows,
// 8 edges/inst for 32-f rows) — round-5 showed per-request overhead (~21 cy)
// is the limiter, so we cut request count 4-8x per edge.

#define SCAN_CHUNK 1024
#define BSHIFT 7
#define BSIZE 128            // dsts per bucket
#define B1 256               // blocks in hist/binscatter passes

__device__ inline void f4fma(float4& a, float s, const float4& b) {
    a.x = fmaf(s, b.x, a.x); a.y = fmaf(s, b.y, a.y);
    a.z = fmaf(s, b.z, a.z); a.w = fmaf(s, b.w, a.w);
}
__device__ inline void f4add(float4& a, const float4& b) {
    a.x += b.x; a.y += b.y; a.z += b.z; a.w += b.w;
}
__device__ inline void f4red(float4& a, int off) {
    a.x += __shfl_xor(a.x, off); a.y += __shfl_xor(a.y, off);
    a.z += __shfl_xor(a.z, off); a.w += __shfl_xor(a.w, off);
}

// ---- generic exclusive scan (m ints, nblk = ceil(m/1024) <= 256) ----
__global__ void k_gscan1(const int* __restrict__ in, int* __restrict__ part, int m) {
    int t = threadIdx.x;
    int base = blockIdx.x * SCAN_CHUNK + t * 4;
    int s = 0;
    for (int u = 0; u < 4; ++u) { int i = base + u; if (i < m) s += in[i]; }
    for (int o = 32; o; o >>= 1) s += __shfl_down(s, o);
    __shared__ int ws[4];
    if ((t & 63) == 0) ws[t >> 6] = s;
    __syncthreads();
    if (t == 0) part[blockIdx.x] = ws[0] + ws[1] + ws[2] + ws[3];
}

__global__ void k_gscan2(const int* __restrict__ in, const int* __restrict__ part,
                         int* __restrict__ out, int m, int nblk) {
    int t = threadIdx.x;
    int b = blockIdx.x;
    int pv = (t < b && t < nblk) ? part[t] : 0;
    int ps = pv;
    for (int o = 32; o; o >>= 1) ps += __shfl_down(ps, o);
    __shared__ int sh[4];
    if ((t & 63) == 0) sh[t >> 6] = ps;
    __syncthreads();
    int blockoff = sh[0] + sh[1] + sh[2] + sh[3];

    int base = b * SCAN_CHUNK + t * 4;
    int v0 = 0, v1 = 0, v2 = 0, v3 = 0;
    if (base + 0 < m) v0 = in[base + 0];
    if (base + 1 < m) v1 = in[base + 1];
    if (base + 2 < m) v2 = in[base + 2];
    if (base + 3 < m) v3 = in[base + 3];
    int tot = v0 + v1 + v2 + v3;
    int lane = t & 63, wid = t >> 6;
    int incl = tot;
    for (int o = 1; o < 64; o <<= 1) { int u = __shfl_up(incl, o); if (lane >= o) incl += u; }
    int excl = incl - tot;
    __shared__ int wt[4];
    if (lane == 63) wt[wid] = incl;
    __syncthreads();
    int woff = 0;
    for (int w = 0; w < wid; ++w) woff += wt[w];
    int off = blockoff + woff + excl;
    if (base + 0 < m) out[base + 0] = off;
    if (base + 1 < m) out[base + 1] = off + v0;
    if (base + 2 < m) out[base + 2] = off + v0 + v1;
    if (base + 3 < m) out[base + 3] = off + v0 + v1 + v2;
}

// ---- pass 1a: per-block bucket histogram (LDS atomics only) ----
__global__ __launch_bounds__(256) void k_hist(const int* __restrict__ dst,
                                              int* __restrict__ ghist,
                                              int e, int echunk, int nbuck) {
    extern __shared__ int h[];   // nbuck ints
    int t = threadIdx.x, b = blockIdx.x;
    for (int i = t; i < nbuck; i += 256) h[i] = 0;
    __syncthreads();
    int s = b * echunk, epd = min(e, s + echunk);
    for (int i = s + t; i < epd; i += 256)
        atomicAdd(&h[dst[i] >> BSHIFT], 1);
    __syncthreads();
    for (int k = t; k < nbuck; k += 256)
        ghist[k * B1 + b] = h[k];
}

// ---- pass 1b: scatter packed (src<<7|dlow) into bucket-ordered ebuf ----
__global__ __launch_bounds__(256) void k_binscatter(
        const int* __restrict__ src, const int* __restrict__ dst,
        const int* __restrict__ ghist_s, int* __restrict__ ebuf,
        int e, int echunk, int nbuck) {
    extern __shared__ int cur[];   // nbuck ints
    int t = threadIdx.x, b = blockIdx.x;
    for (int k = t; k < nbuck; k += 256)
        cur[k] = ghist_s[k * B1 + b];
    __syncthreads();
    int s = b * echunk, epd = min(e, s + echunk);
    for (int i = s + t; i < epd; i += 256) {
        int d = dst[i];
        int pos = atomicAdd(&cur[d >> BSHIFT], 1);
        ebuf[pos] = (src[i] << BSHIFT) | (d & (BSIZE - 1));
    }
}

// ---- pass 2: per-bucket count/scan -> rowptr/degi/dis + csr scatter ----
__global__ __launch_bounds__(256) void k_bucket(
        const int* __restrict__ ebuf, const int* __restrict__ ghist_s,
        int* __restrict__ rowptr, int* __restrict__ degi, float* __restrict__ dis,
        int* __restrict__ csr_src, int n, int e, int nbuck) {
    int k = blockIdx.x, t = threadIdx.x;
    int estart = ghist_s[k * B1];
    int eend = (k + 1 < nbuck) ? ghist_s[(k + 1) * B1] : e;
    __shared__ int cnt[BSIZE];
    __shared__ int cur[BSIZE];
    __shared__ int wt[4];
    if (t < BSIZE) cnt[t] = 0;
    __syncthreads();
    for (int i = estart + t; i < eend; i += 256)
        atomicAdd(&cnt[ebuf[i] & (BSIZE - 1)], 1);
    __syncthreads();
    int v = (t < BSIZE) ? cnt[t] : 0;
    int lane = t & 63, wid = t >> 6;
    int incl = v;
    for (int o = 1; o < 64; o <<= 1) { int u = __shfl_up(incl, o); if (lane >= o) incl += u; }
    if (lane == 63) wt[wid] = incl;
    __syncthreads();
    int woff = (wid == 1) ? wt[0] : 0;
    int excl = woff + incl - v;
    if (t < BSIZE) {
        cur[t] = excl;
        int node = k * BSIZE + t;
        if (node < n) {
            rowptr[node] = estart + excl;
            degi[node]   = v;
            dis[node]    = rsqrtf((float)(v + 1));
        }
    }
    __syncthreads();
    for (int i = estart + t; i < eend; i += 256) {
        int w = ebuf[i];
        int pos = estart + atomicAdd(&cur[w & (BSIZE - 1)], 1);
        csr_src[pos] = ((unsigned)w) >> BSHIFT;
    }
}

// h1s = (x @ W1) * dis — outer-product GEMM, block tile 64x64, K=128.
#define SA 132
__global__ __launch_bounds__(256) void k_gemm1(
        const float* __restrict__ x, const float* __restrict__ W1,
        const float* __restrict__ dis, float* __restrict__ h1s, int n) {
    __shared__ float Xs[64 * SA];    // 33 KB
    __shared__ float Ws[128 * 64];   // 32 KB
    int t = threadIdx.x;
    int nbase = blockIdx.x * 64;
    for (int i = t; i < 2048; i += 256)
        ((float4*)Ws)[i] = ((const float4*)W1)[i];
    for (int i = t; i < 2048; i += 256) {
        int row = i >> 5, q = i & 31;
        int r = nbase + row; if (r >= n) r = n - 1;
        float4 v = ((const float4*)(x + (size_t)r * 128))[q];
        *(float4*)&Xs[row * SA + q * 4] = v;
    }
    __syncthreads();
    int wid = t >> 6, lane = t & 63;
    int lx = lane & 7, ly = lane >> 3;
    int wm = wid & 1, wn = wid >> 1;
    int row0 = wm * 32 + ly * 4;
    int col0 = wn * 32 + lx * 4;
    float4 acc0 = {0.f,0.f,0.f,0.f}, acc1 = acc0, acc2 = acc0, acc3 = acc0;
#pragma unroll 4
    for (int k4 = 0; k4 < 32; ++k4) {
        int k = k4 * 4;
        float4 a0 = *(const float4*)&Xs[(row0 + 0) * SA + k];
        float4 a1 = *(const float4*)&Xs[(row0 + 1) * SA + k];
        float4 a2 = *(const float4*)&Xs[(row0 + 2) * SA + k];
        float4 a3 = *(const float4*)&Xs[(row0 + 3) * SA + k];
        float4 b0 = *(const float4*)&Ws[(k + 0) * 64 + col0];
        float4 b1 = *(const float4*)&Ws[(k + 1) * 64 + col0];
        float4 b2 = *(const float4*)&Ws[(k + 2) * 64 + col0];
        float4 b3 = *(const float4*)&Ws[(k + 3) * 64 + col0];
        f4fma(acc0, a0.x, b0); f4fma(acc0, a0.y, b1); f4fma(acc0, a0.z, b2); f4fma(acc0, a0.w, b3);
        f4fma(acc1, a1.x, b0); f4fma(acc1, a1.y, b1); f4fma(acc1, a1.z, b2); f4fma(acc1, a1.w, b3);
        f4fma(acc2, a2.x, b0); f4fma(acc2, a2.y, b1); f4fma(acc2, a2.z, b2); f4fma(acc2, a2.w, b3);
        f4fma(acc3, a3.x, b0); f4fma(acc3, a3.y, b1); f4fma(acc3, a3.z, b2); f4fma(acc3, a3.w, b3);
    }
    int grow = nbase + row0;
#pragma unroll
    for (int r = 0; r < 4; ++r) {
        int rr = grow + r;
        if (rr < n) {
            float d = dis[rr];
            float4 o = (r == 0) ? acc0 : (r == 1) ? acc1 : (r == 2) ? acc2 : acc3;
            o.x *= d; o.y *= d; o.z *= d; o.w *= d;
            *(float4*)&h1s[(size_t)rr * 64 + col0] = o;
        }
    }
}

// h1r[d,:] = relu(dis[d]*(sum_in h1s[s,:] + h1s[d,:]) + b1)
// wave per dst; lane = (edge-slot eg = lane>>4, feat-quad fq=(lane&15)*4).
// One dwordx4 gather covers 4 edges x 256 B. CSR indices staged in a register
// (one coalesced load) and distributed by shfl. xor-16/32 merges edge slots.
__global__ void k_agg1(const float* __restrict__ h1s, const int* __restrict__ csr_src,
                       const int* __restrict__ rowptr, const int* __restrict__ degi,
                       const float* __restrict__ dis, const float* __restrict__ b1,
                       float* __restrict__ h1r, int n) {
    int wid = threadIdx.x >> 6, lane = threadIdx.x & 63;
    int v = blockIdx.x * 4 + wid;
    if (v >= n) return;
    int start = rowptr[v], cnt = degi[v];
    int eg = lane >> 4;
    int fq = (lane & 15) * 4;
    float4 acc = {0.f, 0.f, 0.f, 0.f};
    if (cnt > 0 && cnt <= 64) {
        int pre = csr_src[start + min(lane, cnt - 1)];
        int ng = cnt >> 2;
#pragma unroll 4
        for (int g = 0; g < ng; ++g) {
            int s = __shfl(pre, g * 4 + eg);
            f4add(acc, *(const float4*)&h1s[(size_t)s * 64 + fq]);
        }
        int rem = cnt & 3, j0 = cnt & ~3;
        if (rem) {
            int s = __shfl(pre, j0 + (eg < rem ? eg : 0));
            float4 a = *(const float4*)&h1s[(size_t)s * 64 + fq];
            if (eg < rem) f4add(acc, a);
        }
    } else if (cnt > 64) {
        int j = 0;
        for (; j + 4 <= cnt; j += 4) {
            int s = csr_src[start + j + eg];
            f4add(acc, *(const float4*)&h1s[(size_t)s * 64 + fq]);
        }
        int rem = cnt - j;
        if (rem) {
            int s = csr_src[start + j + (eg < rem ? eg : 0)];
            float4 a = *(const float4*)&h1s[(size_t)s * 64 + fq];
            if (eg < rem) f4add(acc, a);
        }
    }
    if (eg == 0) f4add(acc, *(const float4*)&h1s[(size_t)v * 64 + fq]);  // self
    f4red(acc, 16); f4red(acc, 32);
    if (eg == 0) {
        float d = dis[v];
        float4 bq = *(const float4*)&b1[fq];
        float4 o;
        o.x = fmaxf(fmaf(d, acc.x, bq.x), 0.f);
        o.y = fmaxf(fmaf(d, acc.y, bq.y), 0.f);
        o.z = fmaxf(fmaf(d, acc.z, bq.z), 0.f);
        o.w = fmaxf(fmaf(d, acc.w, bq.w), 0.f);
        *(float4*)&h1r[(size_t)v * 64 + fq] = o;
    }
}

// h2s = (h1r @ W2) * dis — outer-product GEMM, block tile 128x32, K=64.
#define SB 68
__global__ __launch_bounds__(256) void k_gemm2(
        const float* __restrict__ h1r, const float* __restrict__ W2,
        const float* __restrict__ dis, float* __restrict__ h2s, int n) {
    __shared__ float Xs[128 * SB];   // 34.8 KB
    __shared__ float Ws[64 * 32];    // 8 KB
    int t = threadIdx.x;
    int nbase = blockIdx.x * 128;
    for (int i = t; i < 512; i += 256)
        ((float4*)Ws)[i] = ((const float4*)W2)[i];
    for (int i = t; i < 2048; i += 256) {
        int row = i >> 4, q = i & 15;
        int r = nbase + row; if (r >= n) r = n - 1;
        float4 v = ((const float4*)(h1r + (size_t)r * 64))[q];
        *(float4*)&Xs[row * SB + q * 4] = v;
    }
    __syncthreads();
    int wid = t >> 6, lane = t & 63;
    int lx = lane & 7, ly = lane >> 3;
    int row0 = wid * 32 + ly * 4;
    int col0 = lx * 4;
    float4 acc0 = {0.f,0.f,0.f,0.f}, acc1 = acc0, acc2 = acc0, acc3 = acc0;
#pragma unroll 4
    for (int k4 = 0; k4 < 16; ++k4) {
        int k = k4 * 4;
        float4 a0 = *(const float4*)&Xs[(row0 + 0) * SB + k];
        float4 a1 = *(const float4*)&Xs[(row0 + 1) * SB + k];
        float4 a2 = *(const float4*)&Xs[(row0 + 2) * SB + k];
        float4 a3 = *(const float4*)&Xs[(row0 + 3) * SB + k];
        float4 b0 = *(const float4*)&Ws[(k + 0) * 32 + col0];
        float4 b1 = *(const float4*)&Ws[(k + 1) * 32 + col0];
        float4 b2 = *(const float4*)&Ws[(k + 2) * 32 + col0];
        float4 b3 = *(const float4*)&Ws[(k + 3) * 32 + col0];
        f4fma(acc0, a0.x, b0); f4fma(acc0, a0.y, b1); f4fma(acc0, a0.z, b2); f4fma(acc0, a0.w, b3);
        f4fma(acc1, a1.x, b0); f4fma(acc1, a1.y, b1); f4fma(acc1, a1.z, b2); f4fma(acc1, a1.w, b3);
        f4fma(acc2, a2.x, b0); f4fma(acc2, a2.y, b1); f4fma(acc2, a2.z, b2); f4fma(acc2, a2.w, b3);
        f4fma(acc3, a3.x, b0); f4fma(acc3, a3.y, b1); f4fma(acc3, a3.z, b2); f4fma(acc3, a3.w, b3);
    }
    int grow = nbase + row0;
#pragma unroll
    for (int r = 0; r < 4; ++r) {
        int rr = grow + r;
        if (rr < n) {
            float d = dis[rr];
            float4 o = (r == 0) ? acc0 : (r == 1) ? acc1 : (r == 2) ? acc2 : acc3;
            o.x *= d; o.y *= d; o.z *= d; o.w *= d;
            *(float4*)&h2s[(size_t)rr * 32 + col0] = o;
        }
    }
}

// layer-2 aggregation + relu + FC head, fused.
// wave per dst; lane = (edge-slot eg = lane>>3 [8 slots], fq=(lane&7)*4).
// One dwordx4 gather covers 8 edges x 128 B. xor-8/16/32 merge; FC dot in
// lanes 0-7 then xor-1/2/4.
__global__ void k_agg2(const float* __restrict__ h2s, const int* __restrict__ csr_src,
                       const int* __restrict__ rowptr, const int* __restrict__ degi,
                       const float* __restrict__ dis, const float* __restrict__ b2,
                       const float* __restrict__ Wfc, const float* __restrict__ bfc,
                       float* __restrict__ out, int n) {
    int wid = threadIdx.x >> 6, lane = threadIdx.x & 63;
    int v = blockIdx.x * 4 + wid;
    if (v >= n) return;
    int start = rowptr[v], cnt = degi[v];
    int eg = lane >> 3;
    int fq = (lane & 7) * 4;
    float4 acc = {0.f, 0.f, 0.f, 0.f};
    if (cnt > 0 && cnt <= 64) {
        int pre = csr_src[start + min(lane, cnt - 1)];
        int ng = cnt >> 3;
#pragma unroll 4
        for (int g = 0; g < ng; ++g) {
            int s = __shfl(pre, g * 8 + eg);
            f4add(acc, *(const float4*)&h2s[(size_t)s * 32 + fq]);
        }
        int rem = cnt & 7, j0 = cnt & ~7;
        if (rem) {
            int s = __shfl(pre, j0 + (eg < rem ? eg : 0));
            float4 a = *(const float4*)&h2s[(size_t)s * 32 + fq];
            if (eg < rem) f4add(acc, a);
        }
    } else if (cnt > 64) {
        int j = 0;
        for (; j + 8 <= cnt; j += 8) {
            int s = csr_src[start + j + eg];
            f4add(acc, *(const float4*)&h2s[(size_t)s * 32 + fq]);
        }
        int rem = cnt - j;
        if (rem) {
            int s = csr_src[start + j + (eg < rem ? eg : 0)];
            float4 a = *(const float4*)&h2s[(size_t)s * 32 + fq];
            if (eg < rem) f4add(acc, a);
        }
    }
    if (eg == 0) f4add(acc, *(const float4*)&h2s[(size_t)v * 32 + fq]);  // self
    f4red(acc, 8); f4red(acc, 16); f4red(acc, 32);
    float p = 0.f;
    if (eg == 0) {
        float d = dis[v];
        float4 bq = *(const float4*)&b2[fq];
        float4 wq = *(const float4*)&Wfc[fq];
        p  = fmaxf(fmaf(d, acc.x, bq.x), 0.f) * wq.x;
        p += fmaxf(fmaf(d, acc.y, bq.y), 0.f) * wq.y;
        p += fmaxf(fmaf(d, acc.z, bq.z), 0.f) * wq.z;
        p += fmaxf(fmaf(d, acc.w, bq.w), 0.f) * wq.w;
    }
    p += __shfl_xor(p, 1); p += __shfl_xor(p, 2); p += __shfl_xor(p, 4);
    if (lane == 0) out[v] = p + bfc[0];
}

extern "C" void kernel_launch(void* const* d_in, const int* in_sizes, int n_in,
                              void* d_out, int out_size, void* d_ws, size_t ws_size,
                              hipStream_t stream) {
    const float* x   = (const float*)d_in[0];
    const int*   ei  = (const int*)d_in[1];
    const float* W1  = (const float*)d_in[2];
    const float* b1  = (const float*)d_in[3];
    const float* W2  = (const float*)d_in[4];
    const float* b2  = (const float*)d_in[5];
    const float* Wfc = (const float*)d_in[6];
    const float* bfc = (const float*)d_in[7];
    float* out = (float*)d_out;

    const int n = in_sizes[0] / 128;       // 100000
    const int e = in_sizes[1] / 2;         // 3200000
    const int* src = ei;
    const int* dst = ei + e;

    const int nbuck = (n + BSIZE - 1) / BSIZE;           // 782
    const int m = nbuck * B1;                            // 200192
    const int echunk = (e + B1 - 1) / B1;                // 12500

    char* p = (char*)d_ws;
    size_t off = 0;
    auto carve = [&](size_t bytes) { void* r = p + off; off = (off + bytes + 255) & ~(size_t)255; return r; };
    int*   ghist   = (int*)  carve((size_t)m * 4);
    int*   ghist_s = (int*)  carve((size_t)m * 4);
    int*   part    = (int*)  carve(256 * 4);
    int*   rowptr  = (int*)  carve((size_t)n * 4);
    int*   degi    = (int*)  carve((size_t)n * 4);
    float* dis     = (float*)carve((size_t)n * 4);
    int*   csr_src = (int*)  carve((size_t)e * 4);
    void*  ebuf_or_h1s = carve((size_t)n * 64 * 4);      // ebuf(E*4) aliases h1s(N*64*4)
    float* h1r     = (float*)carve((size_t)n * 64 * 4);
    float* h2s     = (float*)carve((size_t)n * 32 * 4);
    int*   ebuf = (int*)ebuf_or_h1s;
    float* h1s  = (float*)ebuf_or_h1s;
    (void)ws_size;

    const int nblk_scan = (m + SCAN_CHUNK - 1) / SCAN_CHUNK;   // 196 (<=256)
    const size_t lds_buck = (size_t)nbuck * 4;

    k_hist<<<B1, 256, lds_buck, stream>>>(dst, ghist, e, echunk, nbuck);
    k_gscan1<<<nblk_scan, 256, 0, stream>>>(ghist, part, m);
    k_gscan2<<<nblk_scan, 256, 0, stream>>>(ghist, part, ghist_s, m, nblk_scan);
    k_binscatter<<<B1, 256, lds_buck, stream>>>(src, dst, ghist_s, ebuf, e, echunk, nbuck);
    k_bucket<<<nbuck, 256, 0, stream>>>(ebuf, ghist_s, rowptr, degi, dis, csr_src, n, e, nbuck);
    k_gemm1<<<(n + 63) / 64, 256, 0, stream>>>(x, W1, dis, h1s, n);
    k_agg1<<<(n + 3) / 4, 256, 0, stream>>>(h1s, csr_src, rowptr, degi, dis, b1, h1r, n);
    k_gemm2<<<(n + 127) / 128, 256, 0, stream>>>(h1r, W2, dis, h2s, n);
    k_agg2<<<(n + 3) / 4, 256, 0, stream>>>(h2s, csr_src, rowptr, degi, dis, b2, Wfc, bfc, out, n);
}